// Round 11
// baseline (276.966 us; speedup 1.0000x reference)
//
#include <hip/hip_runtime.h>
#include <hip/hip_bf16.h>
#include <cstdint>
#include <cstddef>

#define D_MODEL 1024
#define NHEADS  16
#define HDIM    64
#define HALFW   32
#define BATCH   4
#define SEQ     4096
#define MROWS   (BATCH*SEQ)

typedef __attribute__((ext_vector_type(8))) short        bf16x8;
typedef __attribute__((ext_vector_type(4))) float        f32x4;
typedef __attribute__((ext_vector_type(4))) unsigned int u32x4;

typedef const __attribute__((address_space(1))) void gvoid_t;
typedef __attribute__((address_space(3))) void       lvoid_t;

__device__ __forceinline__ unsigned short f2bf(float f) {
    unsigned int u = __float_as_uint(f);
    u += 0x7fffu + ((u >> 16) & 1u);   // RNE
    return (unsigned short)(u >> 16);
}

// XOR swizzle for row-major [R][128] bf16 LDS tiles (256B rows) - attn kernel.
__device__ __forceinline__ int vswz(int row, int bytecol) {
    return (row * 256 + bytecol) ^ (((row ^ (row >> 3)) & 7) << 4);
}

// ---------------- f32 -> bf16 conversion (vectorized, 8 elems/thread) ----------
__global__ __launch_bounds__(256)
void cvt_f32_bf16(const float* __restrict__ src, unsigned short* __restrict__ dst, int n8) {
    int i = blockIdx.x * 256 + threadIdx.x;
    if (i >= n8) return;
    float4 a = *(const float4*)(src + (size_t)i * 8);
    float4 b = *(const float4*)(src + (size_t)i * 8 + 4);
    u32x4 o;
    o[0] = (unsigned)f2bf(a.x) | ((unsigned)f2bf(a.y) << 16);
    o[1] = (unsigned)f2bf(a.z) | ((unsigned)f2bf(a.w) << 16);
    o[2] = (unsigned)f2bf(b.x) | ((unsigned)f2bf(b.y) << 16);
    o[3] = (unsigned)f2bf(b.z) | ((unsigned)f2bf(b.w) << 16);
    *(u32x4*)(dst + (size_t)i * 8) = o;
}

__global__ __launch_bounds__(256)
void cvt4_f32_bf16(const float* __restrict__ s0, const float* __restrict__ s1,
                   const float* __restrict__ s2, const float* __restrict__ s3,
                   unsigned short* __restrict__ d0, unsigned short* __restrict__ d1,
                   unsigned short* __restrict__ d2, unsigned short* __restrict__ d3, int n8) {
    int i = blockIdx.x * 256 + threadIdx.x;
    if (i >= n8) return;
    const float* src = blockIdx.y == 0 ? s0 : blockIdx.y == 1 ? s1 : blockIdx.y == 2 ? s2 : s3;
    unsigned short* dst = blockIdx.y == 0 ? d0 : blockIdx.y == 1 ? d1 : blockIdx.y == 2 ? d2 : d3;
    float4 a = *(const float4*)(src + (size_t)i * 8);
    float4 b = *(const float4*)(src + (size_t)i * 8 + 4);
    u32x4 o;
    o[0] = (unsigned)f2bf(a.x) | ((unsigned)f2bf(a.y) << 16);
    o[1] = (unsigned)f2bf(a.z) | ((unsigned)f2bf(a.w) << 16);
    o[2] = (unsigned)f2bf(b.x) | ((unsigned)f2bf(b.y) << 16);
    o[3] = (unsigned)f2bf(b.z) | ((unsigned)f2bf(b.w) << 16);
    *(u32x4*)(dst + (size_t)i * 8) = o;
}

// ---- 256x128 bf16 GEMM (B^T), A double-buffered in LDS, B DIRECT-GLOBAL ----
// LDS per half-tile: A stage 16KB + A frag reads 32KB (was 72KB with B staged)
// -> LDS no longer the most-loaded resource; B frags come per-lane from
// L2-hot weights (16 consecutive rows x 64B per wave-op). 32KB LDS,
// 2 blocks/CU. XCD swizzle rb-INNER: W panel (256KB) stays L2-hot across 8
// consecutive blocks on the same XCD. A-LDS chunk swizzle: chunk c of row r
// at position (c+(r>>1))&3 -> conflict-free b128 frag reads.
template <int NOUT, int F32OUT>
__global__ __launch_bounds__(256, 2)
void gemm_bd(const unsigned short* __restrict__ A,
             const unsigned short* __restrict__ W0,
             const unsigned short* __restrict__ W1,
             const unsigned short* __restrict__ W2,
             const float* __restrict__ b0, const float* __restrict__ b1,
             const float* __restrict__ b2,
             unsigned short* __restrict__ o0, unsigned short* __restrict__ o1,
             unsigned short* __restrict__ o2, float* __restrict__ of32)
{
    constexpr int K  = 1024;
    constexpr int HT = K / 32;
    constexpr int CBG = 8 * NOUT;
    __shared__ unsigned short lds[2 * 8192];   // 2 slots x A 16KB

    const int tid  = threadIdx.x;
    const int wave = tid >> 6, lane = tid & 63;
    const int wr = wave >> 1, wc = wave & 1;

    // XCD swizzle, rb inner (W-panel L2 locality)
    const int bid = blockIdx.x;
    const int x   = bid & 7;
    const int lw  = bid >> 3;            // [0, 8*CBG)
    const int cbg = lw >> 3;
    const int rb  = x * 8 + (lw & 7);
    const int which = cbg >> 3;
    const int bm = rb * 256, bn = (cbg & 7) * 128;

    const unsigned short* W = (NOUT == 1 || which == 0) ? W0 : (which == 1 ? W1 : W2);
    const float* bias       = (NOUT == 1 || which == 0) ? b0 : (which == 1 ? b1 : b2);
    unsigned short* obf     = (NOUT == 1 || which == 0) ? o0 : (which == 1 ? o1 : o2);

    f32x4 acc[8][4];
    #pragma unroll
    for (int m = 0; m < 8; ++m)
        #pragma unroll
        for (int n = 0; n < 4; ++n)
            #pragma unroll
            for (int j = 0; j < 4; ++j) acc[m][n][j] = 0.0f;

    char* ldsb = (char*)lds;

    // A staging: 4 chunks/thread (rows ra+64i)
    const int ra  = tid >> 2;
    const int ks  = ((tid & 3) - (ra >> 1)) & 3;
    const size_t sA[4] = { (size_t)(bm + ra) * K + ks * 8,
                           (size_t)(bm + ra + 64)  * K + ks * 8,
                           (size_t)(bm + ra + 128) * K + ks * 8,
                           (size_t)(bm + ra + 192) * K + ks * 8 };
    const int ldsW = wave * 1024;

    auto STAGE_A = [&](int h) {
        const int slot = (h & 1) * 16384;
        const int ke = h * 32;
        #pragma unroll
        for (int i = 0; i < 4; ++i)
            __builtin_amdgcn_global_load_lds((gvoid_t*)(A + sA[i] + ke),
                (lvoid_t*)(ldsb + slot + ldsW + i * 4096), 16, 0, 0);
    };

    const int lr = lane & 15;
    const int pp = (((lane >> 4) + (lr >> 1)) & 3) << 4;
    const int abase = (wr * 128 + lr) * 64 + pp;
    // B fragment global rows (fixed) and per-h k-offset
    const unsigned short* wrow[4];
    #pragma unroll
    for (int n = 0; n < 4; ++n)
        wrow[n] = W + (size_t)(bn + wc * 64 + n * 16 + lr) * K + (lane >> 4) * 8;

    STAGE_A(0);
    __syncthreads();

    #pragma unroll 1
    for (int h = 0; h < HT; ++h) {
        const char* sl = ldsb + (h & 1) * 16384;
        if (h + 1 < HT) STAGE_A(h + 1);
        bf16x8 fb[4];
        #pragma unroll
        for (int n = 0; n < 4; ++n) fb[n] = *(const bf16x8*)(wrow[n] + h * 32);
        bf16x8 fa[8];
        #pragma unroll
        for (int m = 0; m < 8; ++m) fa[m] = *(const bf16x8*)(sl + abase + m * 1024);
        #pragma unroll
        for (int m = 0; m < 8; ++m)
            #pragma unroll
            for (int n = 0; n < 4; ++n)
                acc[m][n] = __builtin_amdgcn_mfma_f32_16x16x32_bf16(fa[m], fb[n], acc[m][n], 0, 0, 0);
        __syncthreads();   // drains vmcnt (A h+1 landed); slot safe to reuse
    }

    float bvv[4];
    #pragma unroll
    for (int n = 0; n < 4; ++n) bvv[n] = bias[bn + wc * 64 + n * 16 + lr];
    #pragma unroll
    for (int m = 0; m < 8; ++m) {
        #pragma unroll
        for (int j = 0; j < 4; ++j) {
            const int row = bm + wr * 128 + m * 16 + (lane >> 4) * 4 + j;
            #pragma unroll
            for (int n = 0; n < 4; ++n) {
                const int col = bn + wc * 64 + n * 16 + lr;
                const float v = acc[m][n][j] + bvv[n];
                if (F32OUT) of32[(size_t)row * 1024 + col] = v;
                else        obf[(size_t)row * 1024 + col]  = f2bf(v);
            }
        }
    }
}

// -------- banded attention v3: 32KB LDS (Vt+Ps only), Q/K direct-global ------
__global__ __launch_bounds__(256)
void attn_band(const unsigned short* __restrict__ Q,
               const unsigned short* __restrict__ Kk,
               const unsigned short* __restrict__ V,
               unsigned short* __restrict__ Ctx)
{
    __shared__ unsigned short Vt[64 * 128];   // [hd][key], XOR-swizzled
    __shared__ unsigned short Ps[64 * 128];   // [q][key],  XOR-swizzled

    const int qt = blockIdx.x, h = blockIdx.y, b = blockIdx.z;
    const int qbase  = qt * 64;
    const int kstart = qbase - HALFW;
    const int tid = threadIdx.x, wave = tid >> 6, lane = tid & 63;

    const size_t base = (size_t)b * SEQ * D_MODEL + (size_t)h * HDIM;
    const unsigned short* Qb = Q  + base;
    const unsigned short* Kb = Kk + base;
    const unsigned short* Vb = V  + base;
    unsigned short*       Cb = Ctx + base;

    for (int c = tid; c < 512; c += 256) {
        const int p = c >> 3, dch = c & 7;
        const int k0 = kstart + 2 * p, k1 = k0 + 1;
        u32x4 v0, v1;
        if (k0 >= 0 && k0 < SEQ) {
            v0 = *(const u32x4*)(Vb + (size_t)k0 * D_MODEL + dch * 8);
        } else {
            for (int j = 0; j < 4; ++j) v0[j] = 0u;
        }
        if (k1 >= 0 && k1 < SEQ) {
            v1 = *(const u32x4*)(Vb + (size_t)k1 * D_MODEL + dch * 8);
        } else {
            for (int j = 0; j < 4; ++j) v1[j] = 0u;
        }
        #pragma unroll
        for (int j = 0; j < 8; ++j) {
            const int d = dch * 8 + j;
            const unsigned lo = (v0[j >> 1] >> ((j & 1) * 16)) & 0xffffu;
            const unsigned hi = (v1[j >> 1] >> ((j & 1) * 16)) & 0xffffu;
            *(unsigned*)((char*)Vt + vswz(d, 4 * p)) = lo | (hi << 16);
        }
    }
    __syncthreads();

    f32x4 sc[8];
    #pragma unroll
    for (int c = 0; c < 8; ++c)
        #pragma unroll
        for (int j = 0; j < 4; ++j) sc[c][j] = 0.0f;

    const int fcol = (lane >> 4) * 8;
    bf16x8 aq[2];
    #pragma unroll
    for (int kc = 0; kc < 2; ++kc)
        aq[kc] = *(const bf16x8*)(Qb + (size_t)(qbase + wave * 16 + (lane & 15)) * D_MODEL
                                     + kc * 32 + fcol);
    #pragma unroll
    for (int c = 0; c < 8; ++c) {
        const long krow = (long)kstart + c * 16 + (lane & 15);
        const unsigned short* kp = Kb + krow * (long)D_MODEL + fcol;
        #pragma unroll
        for (int kc = 0; kc < 2; ++kc) {
            bf16x8 bk_ = *(const bf16x8*)(kp + kc * 32);
            sc[c] = __builtin_amdgcn_mfma_f32_16x16x32_bf16(aq[kc], bk_, sc[c], 0, 0, 0);
        }
    }

    const int grp = lane >> 4, colk = lane & 15;
    float rowmax[4] = {-1e30f, -1e30f, -1e30f, -1e30f};
    #pragma unroll
    for (int c = 0; c < 8; ++c) {
        const int kpos = kstart + c * 16 + colk;
        #pragma unroll
        for (int j = 0; j < 4; ++j) {
            const int qpos = qbase + wave * 16 + grp * 4 + j;
            const int rel = kpos - qpos;
            const bool valid = (kpos >= 0) && (kpos < SEQ) && (rel >= -HALFW) && (rel <= HALFW);
            const float v = valid ? sc[c][j] * 0.125f : -1e30f;
            sc[c][j] = v;
            rowmax[j] = fmaxf(rowmax[j], v);
        }
    }
    #pragma unroll
    for (int j = 0; j < 4; ++j)
        #pragma unroll
        for (int m = 1; m < 16; m <<= 1)
            rowmax[j] = fmaxf(rowmax[j], __shfl_xor(rowmax[j], m, 64));

    float rowsum[4] = {0.f, 0.f, 0.f, 0.f};
    #pragma unroll
    for (int c = 0; c < 8; ++c)
        #pragma unroll
        for (int j = 0; j < 4; ++j) {
            const float p = __expf(sc[c][j] - rowmax[j]);
            sc[c][j] = p;
            rowsum[j] += p;
        }
    #pragma unroll
    for (int j = 0; j < 4; ++j)
        #pragma unroll
        for (int m = 1; m < 16; m <<= 1)
            rowsum[j] += __shfl_xor(rowsum[j], m, 64);

    #pragma unroll
    for (int c = 0; c < 8; ++c)
        #pragma unroll
        for (int j = 0; j < 4; ++j)
            *(unsigned short*)((char*)Ps + vswz(wave * 16 + grp * 4 + j, (c * 16 + colk) * 2))
                = f2bf(sc[c][j]);

    f32x4 o[4];
    #pragma unroll
    for (int n = 0; n < 4; ++n)
        #pragma unroll
        for (int j = 0; j < 4; ++j) o[n][j] = 0.0f;
    #pragma unroll
    for (int kc = 0; kc < 4; ++kc) {
        bf16x8 pa = *(const bf16x8*)((const char*)Ps +
                        vswz(wave * 16 + (lane & 15), kc * 64 + (lane >> 4) * 16));
        #pragma unroll
        for (int n = 0; n < 4; ++n) {
            bf16x8 bv_ = *(const bf16x8*)((const char*)Vt +
                            vswz(n * 16 + (lane & 15), kc * 64 + (lane >> 4) * 16));
            o[n] = __builtin_amdgcn_mfma_f32_16x16x32_bf16(pa, bv_, o[n], 0, 0, 0);
        }
    }

    float rinv[4];
    #pragma unroll
    for (int j = 0; j < 4; ++j) rinv[j] = 1.0f / rowsum[j];
    #pragma unroll
    for (int n = 0; n < 4; ++n)
        #pragma unroll
        for (int j = 0; j < 4; ++j) {
            const int q = qbase + wave * 16 + grp * 4 + j;
            Cb[(size_t)q * D_MODEL + n * 16 + colk] = f2bf(o[n][j] * rinv[j]);
        }
}

// ------------------------------------------------------------------------------
extern "C" void kernel_launch(void* const* d_in, const int* in_sizes, int n_in,
                              void* d_out, int out_size, void* d_ws, size_t ws_size,
                              hipStream_t stream)
{
    (void)in_sizes; (void)n_in; (void)out_size; (void)ws_size;
    const float* x  = (const float*)d_in[0];
    const float* Wq = (const float*)d_in[1];
    const float* bq = (const float*)d_in[2];
    const float* Wk = (const float*)d_in[3];
    const float* bk = (const float*)d_in[4];
    const float* Wv = (const float*)d_in[5];
    const float* bv = (const float*)d_in[6];
    const float* Wo = (const float*)d_in[7];
    const float* bo = (const float*)d_in[8];
    float* out = (float*)d_out;

    char* ws = (char*)d_ws;
    unsigned short* xb  = (unsigned short*)ws;                    // 33.5MB
    unsigned short* wqb = (unsigned short*)(ws + 33554432);
    unsigned short* wkb = wqb + 1048576;
    unsigned short* wvb = wkb + 1048576;
    unsigned short* wob = wvb + 1048576;
    unsigned short* qb  = wob + 1048576;
    unsigned short* kb  = qb + (size_t)MROWS * D_MODEL;
    unsigned short* vb  = kb + (size_t)MROWS * D_MODEL;
    unsigned short* ctxb = xb;   // alias: x no longer needed after QKV GEMM

    cvt_f32_bf16<<<dim3(MROWS * D_MODEL / 8 / 256), 256, 0, stream>>>(x, xb, MROWS * D_MODEL / 8);
    cvt4_f32_bf16<<<dim3(D_MODEL * D_MODEL / 8 / 256, 4), 256, 0, stream>>>(
        Wq, Wk, Wv, Wo, wqb, wkb, wvb, wob, D_MODEL * D_MODEL / 8);

    // fused QKV: 64 row-blocks x 24 col-blocks (256x128 tiles), B direct-global
    gemm_bd<3, 0><<<dim3(1536), 256, 0, stream>>>(
        xb, wqb, wkb, wvb, bq, bk, bv, qb, kb, vb, nullptr);

    attn_band<<<dim3(SEQ / 64, NHEADS, BATCH), 256, 0, stream>>>(qb, kb, vb, ctxb);

    gemm_bd<1, 1><<<dim3(512), 256, 0, stream>>>(
        ctxb, wob, wob, wob, bo, bo, bo, nullptr, nullptr, nullptr, out);
}

// Round 12
// 221.574 us; speedup vs baseline: 1.2500x; 1.2500x over previous
//
#include <hip/hip_runtime.h>
#include <hip/hip_bf16.h>
#include <cstdint>
#include <cstddef>

#define D_MODEL 1024
#define NHEADS  16
#define HDIM    64
#define HALFW   32
#define BATCH   4
#define SEQ     4096
#define MROWS   (BATCH*SEQ)

typedef __attribute__((ext_vector_type(8))) short        bf16x8;
typedef __attribute__((ext_vector_type(4))) float        f32x4;
typedef __attribute__((ext_vector_type(4))) unsigned int u32x4;

typedef const __attribute__((address_space(1))) void gvoid_t;
typedef __attribute__((address_space(3))) void       lvoid_t;

__device__ __forceinline__ unsigned short f2bf(float f) {
    unsigned int u = __float_as_uint(f);
    u += 0x7fffu + ((u >> 16) & 1u);   // RNE
    return (unsigned short)(u >> 16);
}

// XOR swizzle for row-major [R][128] bf16 LDS tiles (256B rows) - attn kernel.
__device__ __forceinline__ int vswz(int row, int bytecol) {
    return (row * 256 + bytecol) ^ (((row ^ (row >> 3)) & 7) << 4);
}

// ---------------- f32 -> bf16 conversion (vectorized, 8 elems/thread) ----------
__global__ __launch_bounds__(256)
void cvt_f32_bf16(const float* __restrict__ src, unsigned short* __restrict__ dst, int n8) {
    int i = blockIdx.x * 256 + threadIdx.x;
    if (i >= n8) return;
    float4 a = *(const float4*)(src + (size_t)i * 8);
    float4 b = *(const float4*)(src + (size_t)i * 8 + 4);
    u32x4 o;
    o[0] = (unsigned)f2bf(a.x) | ((unsigned)f2bf(a.y) << 16);
    o[1] = (unsigned)f2bf(a.z) | ((unsigned)f2bf(a.w) << 16);
    o[2] = (unsigned)f2bf(b.x) | ((unsigned)f2bf(b.y) << 16);
    o[3] = (unsigned)f2bf(b.z) | ((unsigned)f2bf(b.w) << 16);
    *(u32x4*)(dst + (size_t)i * 8) = o;
}

__global__ __launch_bounds__(256)
void cvt4_f32_bf16(const float* __restrict__ s0, const float* __restrict__ s1,
                   const float* __restrict__ s2, const float* __restrict__ s3,
                   unsigned short* __restrict__ d0, unsigned short* __restrict__ d1,
                   unsigned short* __restrict__ d2, unsigned short* __restrict__ d3, int n8) {
    int i = blockIdx.x * 256 + threadIdx.x;
    if (i >= n8) return;
    const float* src = blockIdx.y == 0 ? s0 : blockIdx.y == 1 ? s1 : blockIdx.y == 2 ? s2 : s3;
    unsigned short* dst = blockIdx.y == 0 ? d0 : blockIdx.y == 1 ? d1 : blockIdx.y == 2 ? d2 : d3;
    float4 a = *(const float4*)(src + (size_t)i * 8);
    float4 b = *(const float4*)(src + (size_t)i * 8 + 4);
    u32x4 o;
    o[0] = (unsigned)f2bf(a.x) | ((unsigned)f2bf(a.y) << 16);
    o[1] = (unsigned)f2bf(a.z) | ((unsigned)f2bf(a.w) << 16);
    o[2] = (unsigned)f2bf(b.x) | ((unsigned)f2bf(b.y) << 16);
    o[3] = (unsigned)f2bf(b.z) | ((unsigned)f2bf(b.w) << 16);
    *(u32x4*)(dst + (size_t)i * 8) = o;
}

// ------- 256x256 wave-staggered bf16 GEMM (B^T), 8 waves, half-tile=32k ------
// (round-8 best: QKV 108.6us, MfmaUtil 40%.) Ring: 4 slots x 16KB per matrix.
// Waves 0-3 (X) and 4-7 (Y) staggered:
//   S1: X ds_read(hp)               | Y MFMA(hp-1)
//   S2: stage(hp+3) A+B; X MFMA(hp) | Y ds_read(hp); vmcnt ladder 8/4/0
// Conflict-free chunk swizzle: chunk c of row r at position (c+(r>>1))&3.
template <int NOUT, int F32OUT>
__global__ __launch_bounds__(512)
void gemm256(const unsigned short* __restrict__ A,
             const unsigned short* __restrict__ W0,
             const unsigned short* __restrict__ W1,
             const unsigned short* __restrict__ W2,
             const float* __restrict__ b0, const float* __restrict__ b1,
             const float* __restrict__ b2,
             unsigned short* __restrict__ o0, unsigned short* __restrict__ o1,
             unsigned short* __restrict__ o2, float* __restrict__ of32)
{
    constexpr int K  = 1024;
    constexpr int HT = K / 32;
    constexpr int NWG = 64 * 4 * NOUT;
    __shared__ unsigned short lds[65536];

    const int tid  = threadIdx.x;
    const int wave = tid >> 6, lane = tid & 63;
    const int wr = wave >> 2, wc = wave & 3;
    const bool isX = (wr == 0);

    const int bid = blockIdx.x;
    const int g   = (bid & 7) * (NWG / 8) + (bid >> 3);
    const int rb  = g / (4 * NOUT);
    const int cb  = g % (4 * NOUT);
    const int which = cb >> 2;
    const int bm = rb * 256, bn = (cb & 3) * 256;

    const unsigned short* W = (NOUT == 1 || which == 0) ? W0 : (which == 1 ? W1 : W2);
    const float* bias       = (NOUT == 1 || which == 0) ? b0 : (which == 1 ? b1 : b2);
    unsigned short* obf     = (NOUT == 1 || which == 0) ? o0 : (which == 1 ? o1 : o2);

    f32x4 acc[8][4];
    #pragma unroll
    for (int m = 0; m < 8; ++m)
        #pragma unroll
        for (int n = 0; n < 4; ++n)
            #pragma unroll
            for (int j = 0; j < 4; ++j) acc[m][n][j] = 0.0f;

    char* ldsb = (char*)lds;

    const int idx0 = tid, idx1 = tid + 512;
    const int r0 = idx0 >> 2, r1 = idx1 >> 2;
    const int c0 = ((idx0 & 3) - (r0 >> 1)) & 3;
    const int c1 = ((idx1 & 3) - (r1 >> 1)) & 3;
    const size_t sA0 = (size_t)(bm + r0) * K + c0 * 8;
    const size_t sA1 = (size_t)(bm + r1) * K + c1 * 8;
    const size_t sB0 = (size_t)(bn + r0) * K + c0 * 8;
    const size_t sB1 = (size_t)(bn + r1) * K + c1 * 8;
    const int ldsW = wave * 1024;

    auto STAGE = [&](int h, int isA) {
        const int base = (isA ? 0 : 65536) + (h & 3) * 16384 + ldsW;
        const int ke = h * 32;
        const unsigned short* M = isA ? A : W;
        const size_t s0 = isA ? sA0 : sB0;
        const size_t s1 = isA ? sA1 : sB1;
        __builtin_amdgcn_global_load_lds((gvoid_t*)(M + s0 + ke),
            (lvoid_t*)(ldsb + base), 16, 0, 0);
        __builtin_amdgcn_global_load_lds((gvoid_t*)(M + s1 + ke),
            (lvoid_t*)(ldsb + base + 8192), 16, 0, 0);
    };

    const int lr = lane & 15;
    const int pp = (((lane >> 4) + (lr >> 1)) & 3) << 4;
    const int abase = (wr * 128 + lr) * 64 + pp;
    const int bbase = 65536 + (wc * 64 + lr) * 64 + pp;

    STAGE(0, 1); STAGE(0, 0); STAGE(1, 1); STAGE(1, 0); STAGE(2, 1); STAGE(2, 0);
    asm volatile("s_waitcnt vmcnt(8)" ::: "memory");
    __builtin_amdgcn_s_barrier();

    bf16x8 fa[8], fb[4];

    #pragma unroll 1
    for (int hp = 0; hp < HT; ++hp) {
        const int so = (hp & 3) * 16384;
        // ---------------- S1: X reads(hp) | Y MFMA(hp-1) --------------------
        if (isX) {
            #pragma unroll
            for (int m = 0; m < 8; ++m) fa[m] = *(const bf16x8*)(ldsb + so + abase + m * 1024);
            #pragma unroll
            for (int n = 0; n < 4; ++n) fb[n] = *(const bf16x8*)(ldsb + so + bbase + n * 1024);
        } else if (hp > 0) {
            asm volatile("s_waitcnt lgkmcnt(0)" ::: "memory");
            __builtin_amdgcn_sched_barrier(0);
            __builtin_amdgcn_s_setprio(1);
            #pragma unroll
            for (int m = 0; m < 8; ++m)
                #pragma unroll
                for (int n = 0; n < 4; ++n)
                    acc[m][n] = __builtin_amdgcn_mfma_f32_16x16x32_bf16(fa[m], fb[n], acc[m][n], 0, 0, 0);
            __builtin_amdgcn_s_setprio(0);
        }
        __builtin_amdgcn_sched_barrier(0);
        __builtin_amdgcn_s_barrier();
        // ---------------- S2: stage(hp+3); X MFMA(hp) | Y reads(hp) ---------
        if (hp + 3 < HT) { STAGE(hp + 3, 1); STAGE(hp + 3, 0); }
        __builtin_amdgcn_sched_barrier(0);
        if (isX) {
            asm volatile("s_waitcnt lgkmcnt(0)" ::: "memory");
            __builtin_amdgcn_sched_barrier(0);
            __builtin_amdgcn_s_setprio(1);
            #pragma unroll
            for (int m = 0; m < 8; ++m)
                #pragma unroll
                for (int n = 0; n < 4; ++n)
                    acc[m][n] = __builtin_amdgcn_mfma_f32_16x16x32_bf16(fa[m], fb[n], acc[m][n], 0, 0, 0);
            __builtin_amdgcn_s_setprio(0);
        } else {
            #pragma unroll
            for (int m = 0; m < 8; ++m) fa[m] = *(const bf16x8*)(ldsb + so + abase + m * 1024);
            #pragma unroll
            for (int n = 0; n < 4; ++n) fb[n] = *(const bf16x8*)(ldsb + so + bbase + n * 1024);
        }
        __builtin_amdgcn_sched_barrier(0);
        if (hp <= HT - 4)      { asm volatile("s_waitcnt vmcnt(8)" ::: "memory"); }
        else if (hp == HT - 3) { asm volatile("s_waitcnt vmcnt(4)" ::: "memory"); }
        else                   { asm volatile("s_waitcnt vmcnt(0)" ::: "memory"); }
        __builtin_amdgcn_s_barrier();
    }
    if (!isX) {
        asm volatile("s_waitcnt lgkmcnt(0)" ::: "memory");
        __builtin_amdgcn_sched_barrier(0);
        #pragma unroll
        for (int m = 0; m < 8; ++m)
            #pragma unroll
            for (int n = 0; n < 4; ++n)
                acc[m][n] = __builtin_amdgcn_mfma_f32_16x16x32_bf16(fa[m], fb[n], acc[m][n], 0, 0, 0);
    }

    // epilogue: bias + store, n innermost (full 128B lines per 16-lane group)
    float bvv[4];
    #pragma unroll
    for (int n = 0; n < 4; ++n) bvv[n] = bias[bn + wc * 64 + n * 16 + lr];
    #pragma unroll
    for (int m = 0; m < 8; ++m) {
        #pragma unroll
        for (int j = 0; j < 4; ++j) {
            const int row = bm + wr * 128 + m * 16 + (lane >> 4) * 4 + j;
            #pragma unroll
            for (int n = 0; n < 4; ++n) {
                const int col = bn + wc * 64 + n * 16 + lr;
                const float v = acc[m][n][j] + bvv[n];
                if (F32OUT) of32[(size_t)row * 1024 + col] = v;
                else        obf[(size_t)row * 1024 + col]  = f2bf(v);
            }
        }
    }
}

// -------- banded attention v3: 32KB LDS (Vt+Ps only), Q/K direct-global ------
// 1 barrier; OOB K rows read adjacent ws buffers (allocated; masked before
// use); OOB V rows zero-filled in Vt.
__global__ __launch_bounds__(256)
void attn_band(const unsigned short* __restrict__ Q,
               const unsigned short* __restrict__ Kk,
               const unsigned short* __restrict__ V,
               unsigned short* __restrict__ Ctx)
{
    __shared__ unsigned short Vt[64 * 128];   // [hd][key], XOR-swizzled
    __shared__ unsigned short Ps[64 * 128];   // [q][key],  XOR-swizzled

    const int qt = blockIdx.x, h = blockIdx.y, b = blockIdx.z;
    const int qbase  = qt * 64;
    const int kstart = qbase - HALFW;
    const int tid = threadIdx.x, wave = tid >> 6, lane = tid & 63;

    const size_t base = (size_t)b * SEQ * D_MODEL + (size_t)h * HDIM;
    const unsigned short* Qb = Q  + base;
    const unsigned short* Kb = Kk + base;
    const unsigned short* Vb = V  + base;
    unsigned short*       Cb = Ctx + base;

    for (int c = tid; c < 512; c += 256) {
        const int p = c >> 3, dch = c & 7;
        const int k0 = kstart + 2 * p, k1 = k0 + 1;
        u32x4 v0, v1;
        if (k0 >= 0 && k0 < SEQ) {
            v0 = *(const u32x4*)(Vb + (size_t)k0 * D_MODEL + dch * 8);
        } else {
            for (int j = 0; j < 4; ++j) v0[j] = 0u;
        }
        if (k1 >= 0 && k1 < SEQ) {
            v1 = *(const u32x4*)(Vb + (size_t)k1 * D_MODEL + dch * 8);
        } else {
            for (int j = 0; j < 4; ++j) v1[j] = 0u;
        }
        #pragma unroll
        for (int j = 0; j < 8; ++j) {
            const int d = dch * 8 + j;
            const unsigned lo = (v0[j >> 1] >> ((j & 1) * 16)) & 0xffffu;
            const unsigned hi = (v1[j >> 1] >> ((j & 1) * 16)) & 0xffffu;
            *(unsigned*)((char*)Vt + vswz(d, 4 * p)) = lo | (hi << 16);
        }
    }
    __syncthreads();

    f32x4 sc[8];
    #pragma unroll
    for (int c = 0; c < 8; ++c)
        #pragma unroll
        for (int j = 0; j < 4; ++j) sc[c][j] = 0.0f;

    const int fcol = (lane >> 4) * 8;
    bf16x8 aq[2];
    #pragma unroll
    for (int kc = 0; kc < 2; ++kc)
        aq[kc] = *(const bf16x8*)(Qb + (size_t)(qbase + wave * 16 + (lane & 15)) * D_MODEL
                                     + kc * 32 + fcol);
    #pragma unroll
    for (int c = 0; c < 8; ++c) {
        const long krow = (long)kstart + c * 16 + (lane & 15);
        const unsigned short* kp = Kb + krow * (long)D_MODEL + fcol;
        #pragma unroll
        for (int kc = 0; kc < 2; ++kc) {
            bf16x8 bk_ = *(const bf16x8*)(kp + kc * 32);
            sc[c] = __builtin_amdgcn_mfma_f32_16x16x32_bf16(aq[kc], bk_, sc[c], 0, 0, 0);
        }
    }

    const int grp = lane >> 4, colk = lane & 15;
    float rowmax[4] = {-1e30f, -1e30f, -1e30f, -1e30f};
    #pragma unroll
    for (int c = 0; c < 8; ++c) {
        const int kpos = kstart + c * 16 + colk;
        #pragma unroll
        for (int j = 0; j < 4; ++j) {
            const int qpos = qbase + wave * 16 + grp * 4 + j;
            const int rel = kpos - qpos;
            const bool valid = (kpos >= 0) && (kpos < SEQ) && (rel >= -HALFW) && (rel <= HALFW);
            const float v = valid ? sc[c][j] * 0.125f : -1e30f;
            sc[c][j] = v;
            rowmax[j] = fmaxf(rowmax[j], v);
        }
    }
    #pragma unroll
    for (int j = 0; j < 4; ++j)
        #pragma unroll
        for (int m = 1; m < 16; m <<= 1)
            rowmax[j] = fmaxf(rowmax[j], __shfl_xor(rowmax[j], m, 64));

    float rowsum[4] = {0.f, 0.f, 0.f, 0.f};
    #pragma unroll
    for (int c = 0; c < 8; ++c)
        #pragma unroll
        for (int j = 0; j < 4; ++j) {
            const float p = __expf(sc[c][j] - rowmax[j]);
            sc[c][j] = p;
            rowsum[j] += p;
        }
    #pragma unroll
    for (int j = 0; j < 4; ++j)
        #pragma unroll
        for (int m = 1; m < 16; m <<= 1)
            rowsum[j] += __shfl_xor(rowsum[j], m, 64);

    // write P into OWN wave's 16-row stripe (no barrier needed before PV)
    #pragma unroll
    for (int c = 0; c < 8; ++c)
        #pragma unroll
        for (int j = 0; j < 4; ++j)
            *(unsigned short*)((char*)Ps + vswz(wave * 16 + grp * 4 + j, (c * 16 + colk) * 2))
                = f2bf(sc[c][j]);

    f32x4 o[4];
    #pragma unroll
    for (int n = 0; n < 4; ++n)
        #pragma unroll
        for (int j = 0; j < 4; ++j) o[n][j] = 0.0f;
    #pragma unroll
    for (int kc = 0; kc < 4; ++kc) {
        bf16x8 pa = *(const bf16x8*)((const char*)Ps +
                        vswz(wave * 16 + (lane & 15), kc * 64 + (lane >> 4) * 16));
        #pragma unroll
        for (int n = 0; n < 4; ++n) {
            bf16x8 bv_ = *(const bf16x8*)((const char*)Vt +
                            vswz(n * 16 + (lane & 15), kc * 64 + (lane >> 4) * 16));
            o[n] = __builtin_amdgcn_mfma_f32_16x16x32_bf16(pa, bv_, o[n], 0, 0, 0);
        }
    }

    float rinv[4];
    #pragma unroll
    for (int j = 0; j < 4; ++j) rinv[j] = 1.0f / rowsum[j];
    #pragma unroll
    for (int n = 0; n < 4; ++n)
        #pragma unroll
        for (int j = 0; j < 4; ++j) {
            const int q = qbase + wave * 16 + grp * 4 + j;
            Cb[(size_t)q * D_MODEL + n * 16 + colk] = f2bf(o[n][j] * rinv[j]);
        }
}

// ------------------------------------------------------------------------------
extern "C" void kernel_launch(void* const* d_in, const int* in_sizes, int n_in,
                              void* d_out, int out_size, void* d_ws, size_t ws_size,
                              hipStream_t stream)
{
    (void)in_sizes; (void)n_in; (void)out_size; (void)ws_size;
    const float* x  = (const float*)d_in[0];
    const float* Wq = (const float*)d_in[1];
    const float* bq = (const float*)d_in[2];
    const float* Wk = (const float*)d_in[3];
    const float* bk = (const float*)d_in[4];
    const float* Wv = (const float*)d_in[5];
    const float* bv = (const float*)d_in[6];
    const float* Wo = (const float*)d_in[7];
    const float* bo = (const float*)d_in[8];
    float* out = (float*)d_out;

    char* ws = (char*)d_ws;
    unsigned short* xb  = (unsigned short*)ws;
    unsigned short* wqb = (unsigned short*)(ws + 33554432);
    unsigned short* wkb = wqb + 1048576;
    unsigned short* wvb = wkb + 1048576;
    unsigned short* wob = wvb + 1048576;
    unsigned short* qb  = wob + 1048576;
    unsigned short* kb  = qb + (size_t)MROWS * D_MODEL;
    unsigned short* vb  = kb + (size_t)MROWS * D_MODEL;
    unsigned short* ctxb = xb;   // alias: x no longer needed after QKV GEMM

    cvt_f32_bf16<<<dim3(MROWS * D_MODEL / 8 / 256), 256, 0, stream>>>(x, xb, MROWS * D_MODEL / 8);
    cvt4_f32_bf16<<<dim3(D_MODEL * D_MODEL / 8 / 256, 4), 256, 0, stream>>>(
        Wq, Wk, Wv, Wo, wqb, wkb, wvb, wob, D_MODEL * D_MODEL / 8);

    // fused QKV: 64 row-blocks x 12 col-blocks (256^2 tiles), staggered waves
    gemm256<3, 0><<<dim3(768), 512, 0, stream>>>(
        xb, wqb, wkb, wvb, bq, bk, bv, qb, kb, vb, nullptr);

    attn_band<<<dim3(SEQ / 64, NHEADS, BATCH), 256, 0, stream>>>(qb, kb, vb, ctxb);

    gemm256<1, 1><<<dim3(256), 512, 0, stream>>>(
        ctxb, wob, wob, wob, bo, bo, bo, nullptr, nullptr, nullptr, out);
}

// Round 13
// 220.904 us; speedup vs baseline: 1.2538x; 1.0030x over previous
//
#include <hip/hip_runtime.h>
#include <hip/hip_bf16.h>
#include <cstdint>
#include <cstddef>

#define D_MODEL 1024
#define NHEADS  16
#define HDIM    64
#define HALFW   32
#define BATCH   4
#define SEQ     4096
#define MROWS   (BATCH*SEQ)

typedef __attribute__((ext_vector_type(8))) short        bf16x8;
typedef __attribute__((ext_vector_type(4))) float        f32x4;
typedef __attribute__((ext_vector_type(4))) unsigned int u32x4;

typedef const __attribute__((address_space(1))) void gvoid_t;
typedef __attribute__((address_space(3))) void       lvoid_t;

__device__ __forceinline__ unsigned short f2bf(float f) {
    unsigned int u = __float_as_uint(f);
    u += 0x7fffu + ((u >> 16) & 1u);   // RNE
    return (unsigned short)(u >> 16);
}

// XOR swizzle for row-major [R][128] bf16 LDS tiles (256B rows) - attn kernel.
__device__ __forceinline__ int vswz(int row, int bytecol) {
    return (row * 256 + bytecol) ^ (((row ^ (row >> 3)) & 7) << 4);
}

// ------------- single-launch f32->bf16 conversion: x + 4 weight mats ---------
// blocks [0,8192): x (16.8M elems); [8192,8192+4*512): weights (1M each)
__global__ __launch_bounds__(256)
void cvt_all(const float* __restrict__ x,
             const float* __restrict__ w0, const float* __restrict__ w1,
             const float* __restrict__ w2, const float* __restrict__ w3,
             unsigned short* __restrict__ xb,
             unsigned short* __restrict__ d0, unsigned short* __restrict__ d1,
             unsigned short* __restrict__ d2, unsigned short* __restrict__ d3)
{
    const int bid = blockIdx.x;
    const float* src;
    unsigned short* dst;
    size_t i;
    if (bid < 8192) {
        src = x; dst = xb;
        i = (size_t)bid * 256 + threadIdx.x;
    } else {
        const int r = bid - 8192;
        const int w = r >> 9;
        src = w == 0 ? w0 : w == 1 ? w1 : w == 2 ? w2 : w3;
        dst = w == 0 ? d0 : w == 1 ? d1 : w == 2 ? d2 : d3;
        i = (size_t)(r & 511) * 256 + threadIdx.x;
    }
    float4 a = *(const float4*)(src + i * 8);
    float4 b = *(const float4*)(src + i * 8 + 4);
    u32x4 o;
    o[0] = (unsigned)f2bf(a.x) | ((unsigned)f2bf(a.y) << 16);
    o[1] = (unsigned)f2bf(a.z) | ((unsigned)f2bf(a.w) << 16);
    o[2] = (unsigned)f2bf(b.x) | ((unsigned)f2bf(b.y) << 16);
    o[3] = (unsigned)f2bf(b.z) | ((unsigned)f2bf(b.w) << 16);
    *(u32x4*)(dst + i * 8) = o;
}

// ------- 256x256 wave-staggered bf16 GEMM (B^T), 8 waves, half-tile=32k ------
// r12 base (QKV 109us, MfmaUtil 40%) MINUS the sched_barrier(0) order-pinning
// (m141: pinning defeats compiler scheduling). Only rule-#18 fences retained
// (after inline-asm lgkmcnt(0), before register-only MFMA cluster).
//   S1: X ds_read(hp)               | Y MFMA(hp-1)
//   S2: stage(hp+3) A+B; X MFMA(hp) | Y ds_read(hp); vmcnt ladder 8/4/0
// Conflict-free chunk swizzle: chunk c of row r at position (c+(r>>1))&3.
template <int NOUT, int F32OUT>
__global__ __launch_bounds__(512)
void gemm256(const unsigned short* __restrict__ A,
             const unsigned short* __restrict__ W0,
             const unsigned short* __restrict__ W1,
             const unsigned short* __restrict__ W2,
             const float* __restrict__ b0, const float* __restrict__ b1,
             const float* __restrict__ b2,
             unsigned short* __restrict__ o0, unsigned short* __restrict__ o1,
             unsigned short* __restrict__ o2, float* __restrict__ of32)
{
    constexpr int K  = 1024;
    constexpr int HT = K / 32;
    constexpr int NWG = 64 * 4 * NOUT;
    __shared__ unsigned short lds[65536];

    const int tid  = threadIdx.x;
    const int wave = tid >> 6, lane = tid & 63;
    const int wr = wave >> 2, wc = wave & 3;
    const bool isX = (wr == 0);

    const int bid = blockIdx.x;
    const int g   = (bid & 7) * (NWG / 8) + (bid >> 3);
    const int rb  = g / (4 * NOUT);
    const int cb  = g % (4 * NOUT);
    const int which = cb >> 2;
    const int bm = rb * 256, bn = (cb & 3) * 256;

    const unsigned short* W = (NOUT == 1 || which == 0) ? W0 : (which == 1 ? W1 : W2);
    const float* bias       = (NOUT == 1 || which == 0) ? b0 : (which == 1 ? b1 : b2);
    unsigned short* obf     = (NOUT == 1 || which == 0) ? o0 : (which == 1 ? o1 : o2);

    f32x4 acc[8][4];
    #pragma unroll
    for (int m = 0; m < 8; ++m)
        #pragma unroll
        for (int n = 0; n < 4; ++n)
            #pragma unroll
            for (int j = 0; j < 4; ++j) acc[m][n][j] = 0.0f;

    char* ldsb = (char*)lds;

    const int idx0 = tid, idx1 = tid + 512;
    const int r0 = idx0 >> 2, r1 = idx1 >> 2;
    const int c0 = ((idx0 & 3) - (r0 >> 1)) & 3;
    const int c1 = ((idx1 & 3) - (r1 >> 1)) & 3;
    const size_t sA0 = (size_t)(bm + r0) * K + c0 * 8;
    const size_t sA1 = (size_t)(bm + r1) * K + c1 * 8;
    const size_t sB0 = (size_t)(bn + r0) * K + c0 * 8;
    const size_t sB1 = (size_t)(bn + r1) * K + c1 * 8;
    const int ldsW = wave * 1024;

    auto STAGE = [&](int h, int isA) {
        const int base = (isA ? 0 : 65536) + (h & 3) * 16384 + ldsW;
        const int ke = h * 32;
        const unsigned short* M = isA ? A : W;
        const size_t s0 = isA ? sA0 : sB0;
        const size_t s1 = isA ? sA1 : sB1;
        __builtin_amdgcn_global_load_lds((gvoid_t*)(M + s0 + ke),
            (lvoid_t*)(ldsb + base), 16, 0, 0);
        __builtin_amdgcn_global_load_lds((gvoid_t*)(M + s1 + ke),
            (lvoid_t*)(ldsb + base + 8192), 16, 0, 0);
    };

    const int lr = lane & 15;
    const int pp = (((lane >> 4) + (lr >> 1)) & 3) << 4;
    const int abase = (wr * 128 + lr) * 64 + pp;
    const int bbase = 65536 + (wc * 64 + lr) * 64 + pp;

    STAGE(0, 1); STAGE(0, 0); STAGE(1, 1); STAGE(1, 0); STAGE(2, 1); STAGE(2, 0);
    asm volatile("s_waitcnt vmcnt(8)" ::: "memory");
    __builtin_amdgcn_s_barrier();

    bf16x8 fa[8], fb[4];

    #pragma unroll 1
    for (int hp = 0; hp < HT; ++hp) {
        const int so = (hp & 3) * 16384;
        // ---------------- S1: X reads(hp) | Y MFMA(hp-1) --------------------
        if (isX) {
            #pragma unroll
            for (int m = 0; m < 8; ++m) fa[m] = *(const bf16x8*)(ldsb + so + abase + m * 1024);
            #pragma unroll
            for (int n = 0; n < 4; ++n) fb[n] = *(const bf16x8*)(ldsb + so + bbase + n * 1024);
        } else if (hp > 0) {
            asm volatile("s_waitcnt lgkmcnt(0)" ::: "memory");
            __builtin_amdgcn_sched_barrier(0);          // rule #18
            __builtin_amdgcn_s_setprio(1);
            #pragma unroll
            for (int m = 0; m < 8; ++m)
                #pragma unroll
                for (int n = 0; n < 4; ++n)
                    acc[m][n] = __builtin_amdgcn_mfma_f32_16x16x32_bf16(fa[m], fb[n], acc[m][n], 0, 0, 0);
            __builtin_amdgcn_s_setprio(0);
        }
        __builtin_amdgcn_s_barrier();
        // ---------------- S2: stage(hp+3); X MFMA(hp) | Y reads(hp) ---------
        if (hp + 3 < HT) { STAGE(hp + 3, 1); STAGE(hp + 3, 0); }
        if (isX) {
            asm volatile("s_waitcnt lgkmcnt(0)" ::: "memory");
            __builtin_amdgcn_sched_barrier(0);          // rule #18
            __builtin_amdgcn_s_setprio(1);
            #pragma unroll
            for (int m = 0; m < 8; ++m)
                #pragma unroll
                for (int n = 0; n < 4; ++n)
                    acc[m][n] = __builtin_amdgcn_mfma_f32_16x16x32_bf16(fa[m], fb[n], acc[m][n], 0, 0, 0);
            __builtin_amdgcn_s_setprio(0);
        } else {
            #pragma unroll
            for (int m = 0; m < 8; ++m) fa[m] = *(const bf16x8*)(ldsb + so + abase + m * 1024);
            #pragma unroll
            for (int n = 0; n < 4; ++n) fb[n] = *(const bf16x8*)(ldsb + so + bbase + n * 1024);
        }
        if (hp <= HT - 4)      { asm volatile("s_waitcnt vmcnt(8)" ::: "memory"); }
        else if (hp == HT - 3) { asm volatile("s_waitcnt vmcnt(4)" ::: "memory"); }
        else                   { asm volatile("s_waitcnt vmcnt(0)" ::: "memory"); }
        __builtin_amdgcn_s_barrier();
    }
    if (!isX) {
        asm volatile("s_waitcnt lgkmcnt(0)" ::: "memory");
        __builtin_amdgcn_sched_barrier(0);              // rule #18
        #pragma unroll
        for (int m = 0; m < 8; ++m)
            #pragma unroll
            for (int n = 0; n < 4; ++n)
                acc[m][n] = __builtin_amdgcn_mfma_f32_16x16x32_bf16(fa[m], fb[n], acc[m][n], 0, 0, 0);
    }

    // epilogue: bias + store, n innermost (full 128B lines per 16-lane group)
    float bvv[4];
    #pragma unroll
    for (int n = 0; n < 4; ++n) bvv[n] = bias[bn + wc * 64 + n * 16 + lr];
    #pragma unroll
    for (int m = 0; m < 8; ++m) {
        #pragma unroll
        for (int j = 0; j < 4; ++j) {
            const int row = bm + wr * 128 + m * 16 + (lane >> 4) * 4 + j;
            #pragma unroll
            for (int n = 0; n < 4; ++n) {
                const int col = bn + wc * 64 + n * 16 + lr;
                const float v = acc[m][n][j] + bvv[n];
                if (F32OUT) of32[(size_t)row * 1024 + col] = v;
                else        obf[(size_t)row * 1024 + col]  = f2bf(v);
            }
        }
    }
}

// -------- banded attention v3: 32KB LDS (Vt+Ps only), Q/K direct-global ------
__global__ __launch_bounds__(256)
void attn_band(const unsigned short* __restrict__ Q,
               const unsigned short* __restrict__ Kk,
               const unsigned short* __restrict__ V,
               unsigned short* __restrict__ Ctx)
{
    __shared__ unsigned short Vt[64 * 128];   // [hd][key], XOR-swizzled
    __shared__ unsigned short Ps[64 * 128];   // [q][key],  XOR-swizzled

    const int qt = blockIdx.x, h = blockIdx.y, b = blockIdx.z;
    const int qbase  = qt * 64;
    const int kstart = qbase - HALFW;
    const int tid = threadIdx.x, wave = tid >> 6, lane = tid & 63;

    const size_t base = (size_t)b * SEQ * D_MODEL + (size_t)h * HDIM;
    const unsigned short* Qb = Q  + base;
    const unsigned short* Kb = Kk + base;
    const unsigned short* Vb = V  + base;
    unsigned short*       Cb = Ctx + base;

    for (int c = tid; c < 512; c += 256) {
        const int p = c >> 3, dch = c & 7;
        const int k0 = kstart + 2 * p, k1 = k0 + 1;
        u32x4 v0, v1;
        if (k0 >= 0 && k0 < SEQ) {
            v0 = *(const u32x4*)(Vb + (size_t)k0 * D_MODEL + dch * 8);
        } else {
            for (int j = 0; j < 4; ++j) v0[j] = 0u;
        }
        if (k1 >= 0 && k1 < SEQ) {
            v1 = *(const u32x4*)(Vb + (size_t)k1 * D_MODEL + dch * 8);
        } else {
            for (int j = 0; j < 4; ++j) v1[j] = 0u;
        }
        #pragma unroll
        for (int j = 0; j < 8; ++j) {
            const int d = dch * 8 + j;
            const unsigned lo = (v0[j >> 1] >> ((j & 1) * 16)) & 0xffffu;
            const unsigned hi = (v1[j >> 1] >> ((j & 1) * 16)) & 0xffffu;
            *(unsigned*)((char*)Vt + vswz(d, 4 * p)) = lo | (hi << 16);
        }
    }
    __syncthreads();

    f32x4 sc[8];
    #pragma unroll
    for (int c = 0; c < 8; ++c)
        #pragma unroll
        for (int j = 0; j < 4; ++j) sc[c][j] = 0.0f;

    const int fcol = (lane >> 4) * 8;
    bf16x8 aq[2];
    #pragma unroll
    for (int kc = 0; kc < 2; ++kc)
        aq[kc] = *(const bf16x8*)(Qb + (size_t)(qbase + wave * 16 + (lane & 15)) * D_MODEL
                                     + kc * 32 + fcol);
    #pragma unroll
    for (int c = 0; c < 8; ++c) {
        const long krow = (long)kstart + c * 16 + (lane & 15);
        const unsigned short* kp = Kb + krow * (long)D_MODEL + fcol;
        #pragma unroll
        for (int kc = 0; kc < 2; ++kc) {
            bf16x8 bk_ = *(const bf16x8*)(kp + kc * 32);
            sc[c] = __builtin_amdgcn_mfma_f32_16x16x32_bf16(aq[kc], bk_, sc[c], 0, 0, 0);
        }
    }

    const int grp = lane >> 4, colk = lane & 15;
    float rowmax[4] = {-1e30f, -1e30f, -1e30f, -1e30f};
    #pragma unroll
    for (int c = 0; c < 8; ++c) {
        const int kpos = kstart + c * 16 + colk;
        #pragma unroll
        for (int j = 0; j < 4; ++j) {
            const int qpos = qbase + wave * 16 + grp * 4 + j;
            const int rel = kpos - qpos;
            const bool valid = (kpos >= 0) && (kpos < SEQ) && (rel >= -HALFW) && (rel <= HALFW);
            const float v = valid ? sc[c][j] * 0.125f : -1e30f;
            sc[c][j] = v;
            rowmax[j] = fmaxf(rowmax[j], v);
        }
    }
    #pragma unroll
    for (int j = 0; j < 4; ++j)
        #pragma unroll
        for (int m = 1; m < 16; m <<= 1)
            rowmax[j] = fmaxf(rowmax[j], __shfl_xor(rowmax[j], m, 64));

    float rowsum[4] = {0.f, 0.f, 0.f, 0.f};
    #pragma unroll
    for (int c = 0; c < 8; ++c)
        #pragma unroll
        for (int j = 0; j < 4; ++j) {
            const float p = __expf(sc[c][j] - rowmax[j]);
            sc[c][j] = p;
            rowsum[j] += p;
        }
    #pragma unroll
    for (int j = 0; j < 4; ++j)
        #pragma unroll
        for (int m = 1; m < 16; m <<= 1)
            rowsum[j] += __shfl_xor(rowsum[j], m, 64);

    #pragma unroll
    for (int c = 0; c < 8; ++c)
        #pragma unroll
        for (int j = 0; j < 4; ++j)
            *(unsigned short*)((char*)Ps + vswz(wave * 16 + grp * 4 + j, (c * 16 + colk) * 2))
                = f2bf(sc[c][j]);

    f32x4 o[4];
    #pragma unroll
    for (int n = 0; n < 4; ++n)
        #pragma unroll
        for (int j = 0; j < 4; ++j) o[n][j] = 0.0f;
    #pragma unroll
    for (int kc = 0; kc < 4; ++kc) {
        bf16x8 pa = *(const bf16x8*)((const char*)Ps +
                        vswz(wave * 16 + (lane & 15), kc * 64 + (lane >> 4) * 16));
        #pragma unroll
        for (int n = 0; n < 4; ++n) {
            bf16x8 bv_ = *(const bf16x8*)((const char*)Vt +
                            vswz(n * 16 + (lane & 15), kc * 64 + (lane >> 4) * 16));
            o[n] = __builtin_amdgcn_mfma_f32_16x16x32_bf16(pa, bv_, o[n], 0, 0, 0);
        }
    }

    float rinv[4];
    #pragma unroll
    for (int j = 0; j < 4; ++j) rinv[j] = 1.0f / rowsum[j];
    #pragma unroll
    for (int n = 0; n < 4; ++n)
        #pragma unroll
        for (int j = 0; j < 4; ++j) {
            const int q = qbase + wave * 16 + grp * 4 + j;
            Cb[(size_t)q * D_MODEL + n * 16 + colk] = f2bf(o[n][j] * rinv[j]);
        }
}

// ------------------------------------------------------------------------------
extern "C" void kernel_launch(void* const* d_in, const int* in_sizes, int n_in,
                              void* d_out, int out_size, void* d_ws, size_t ws_size,
                              hipStream_t stream)
{
    (void)in_sizes; (void)n_in; (void)out_size; (void)ws_size;
    const float* x  = (const float*)d_in[0];
    const float* Wq = (const float*)d_in[1];
    const float* bq = (const float*)d_in[2];
    const float* Wk = (const float*)d_in[3];
    const float* bk = (const float*)d_in[4];
    const float* Wv = (const float*)d_in[5];
    const float* bv = (const float*)d_in[6];
    const float* Wo = (const float*)d_in[7];
    const float* bo = (const float*)d_in[8];
    float* out = (float*)d_out;

    char* ws = (char*)d_ws;
    unsigned short* xb  = (unsigned short*)ws;
    unsigned short* wqb = (unsigned short*)(ws + 33554432);
    unsigned short* wkb = wqb + 1048576;
    unsigned short* wvb = wkb + 1048576;
    unsigned short* wob = wvb + 1048576;
    unsigned short* qb  = wob + 1048576;
    unsigned short* kb  = qb + (size_t)MROWS * D_MODEL;
    unsigned short* vb  = kb + (size_t)MROWS * D_MODEL;
    unsigned short* ctxb = xb;   // alias: x no longer needed after QKV GEMM

    cvt_all<<<dim3(8192 + 4 * 512), 256, 0, stream>>>(
        x, Wq, Wk, Wv, Wo, xb, wqb, wkb, wvb, wob);

    // fused QKV: 64 row-blocks x 12 col-blocks (256^2 tiles), staggered waves
    gemm256<3, 0><<<dim3(768), 512, 0, stream>>>(
        xb, wqb, wkb, wvb, bq, bk, bv, qb, kb, vb, nullptr);

    attn_band<<<dim3(SEQ / 64, NHEADS, BATCH), 256, 0, stream>>>(qb, kb, vb, ctxb);

    gemm256<1, 1><<<dim3(256), 512, 0, stream>>>(
        ctxb, wob, wob, wob, bo, bo, bo, nullptr, nullptr, nullptr, out);
}